// Round 17
// baseline (4864.340 us; speedup 1.0000x reference)
//
#include <hip/hip_runtime.h>

// LSTM v17 for MI355X.
// v16 (PASSED, 4.51ms) + two critical-path cuts in h-role:
//  1) bottom vmcnt(0) drain DELETED; flag prefetch issued BEFORE publish/out
//     stores so the loop-top flag read waits only on its own load (vmcnt FIFO),
//     and the first poll vmcnt(0) overlaps store-ack with poll RT.
//  2) 24-MFMA dependent chain split into 3 independent 8-deep chains.
// Everything else v16 verbatim. Fallback ws<257MB: v8 xpk (proven 5.19ms).

#define T_STEPS 2048
#define BATCH   64
#define DIM     256
#define HID     256
#define PKEEP   0.7f
#define RPG     16
#define REGION_U32 (RPG * HID * 2)       // 8192 u32
#define PLANE_U32  (4 * REGION_U32)      // 32768 u32 (128KB)
#define XEL     (T_STEPS * BATCH * DIM)
#define NH      64
#define NX      64

typedef __attribute__((ext_vector_type(8))) short s16x8;
typedef __attribute__((ext_vector_type(4))) float f32x4;
typedef __attribute__((ext_vector_type(4))) unsigned int u32x4;
typedef __attribute__((ext_vector_type(2))) unsigned int u32x2;
typedef unsigned int u32;
typedef unsigned short u16;

#define XF_OFF   4096                    // 64 flags, 64B apart
#define HBUF_OFF 16384
#define BIG_OFF  (1 << 20)
#define ZERO_U32 ((HBUF_OFF + 2 * PLANE_U32 * 4) / 4)

#define HISEL 0x07060302u
#define LOSEL 0x05040100u

__device__ __forceinline__ u16 f2bf_rne(float f) {
  unsigned x = __float_as_uint(f);
  return (u16)((x + 0x7fffu + ((x >> 16) & 1u)) >> 16);
}
__device__ __forceinline__ float bf2f(u16 u) { return __uint_as_float(((unsigned)u) << 16); }
__device__ __forceinline__ float sigm(float v) { return 1.0f / (1.0f + __expf(-v)); }
__device__ __forceinline__ float tanh_f(float v) {
  float e = __expf(-2.0f * fabsf(v));
  float r = (1.0f - e) / (1.0f + e);
  return v < 0.0f ? -r : r;
}
__device__ __forceinline__ u32 packbf(float v) {
  u32 uh = __float_as_uint(v) & 0xFFFF0000u;
  u32 lo = (u32)f2bf_rne(v - __uint_as_float(uh));
  return uh | lo;
}
__device__ __forceinline__ void dev_st_u32x2(u32* p, u32x2 v) {
  asm volatile("global_store_dwordx2 %0, %1, off sc0 sc1" :: "v"(p), "v"(v) : "memory");
}
__device__ __forceinline__ void coh_st_i32(int* p, int v) {
  asm volatile("global_store_dword %0, %1, off sc0 sc1" :: "v"(p), "v"(v) : "memory");
}
__device__ __forceinline__ int coh_ld_i32(const int* p) {  // caller/compiler waits
  int v;
  asm volatile("global_load_dword %0, %1, off sc0 sc1" : "=v"(v) : "v"(p) : "memory");
  return v;
}
__device__ __forceinline__ u32x2 coh_ld_u32x2(const u32* p) {  // caller drains
  u32x2 v;
  asm volatile("global_load_dwordx2 %0, %1, off sc0 sc1" : "=v"(v) : "v"(p) : "memory");
  return v;
}
__device__ __forceinline__ void gload_lds16(const u32* g, u32* lds) {
  __builtin_amdgcn_global_load_lds(
      (const __attribute__((address_space(1))) u32*)g,
      (__attribute__((address_space(3))) u32*)lds, 16, 0, 0);
}
__device__ __forceinline__ void unpack8(u32x4 a, u32x4 b, s16x8& hi, s16x8& lo) {
  u32x4 H, L;
  H[0] = __builtin_amdgcn_perm(a[1], a[0], HISEL);
  H[1] = __builtin_amdgcn_perm(a[3], a[2], HISEL);
  H[2] = __builtin_amdgcn_perm(b[1], b[0], HISEL);
  H[3] = __builtin_amdgcn_perm(b[3], b[2], HISEL);
  L[0] = __builtin_amdgcn_perm(a[1], a[0], LOSEL);
  L[1] = __builtin_amdgcn_perm(a[3], a[2], LOSEL);
  L[2] = __builtin_amdgcn_perm(b[1], b[0], LOSEL);
  L[3] = __builtin_amdgcn_perm(b[3], b[2], LOSEL);
  hi = __builtin_bit_cast(s16x8, H);
  lo = __builtin_bit_cast(s16x8, L);
}
// 4x4 reg<->lane-bit transpose (proven v8)
__device__ __forceinline__ void xpose4(f32x4& a, bool b2, bool b3) {
  {
    int t0 = __builtin_amdgcn_ds_swizzle(__float_as_int(a[1]), 0x101F);
    int u0 = __builtin_amdgcn_ds_swizzle(__float_as_int(a[0]), 0x101F);
    int t1 = __builtin_amdgcn_ds_swizzle(__float_as_int(a[3]), 0x101F);
    int u1 = __builtin_amdgcn_ds_swizzle(__float_as_int(a[2]), 0x101F);
    float A0 = b2 ? __int_as_float(t0) : a[0];
    float A1 = b2 ? a[1] : __int_as_float(u0);
    float A2 = b2 ? __int_as_float(t1) : a[2];
    float A3 = b2 ? a[3] : __int_as_float(u1);
    a[0] = A0; a[1] = A1; a[2] = A2; a[3] = A3;
  }
  {
    int t0 = __builtin_amdgcn_ds_swizzle(__float_as_int(a[2]), 0x201F);
    int u0 = __builtin_amdgcn_ds_swizzle(__float_as_int(a[0]), 0x201F);
    int t1 = __builtin_amdgcn_ds_swizzle(__float_as_int(a[3]), 0x201F);
    int u1 = __builtin_amdgcn_ds_swizzle(__float_as_int(a[1]), 0x201F);
    float A0 = b3 ? __int_as_float(t0) : a[0];
    float A2 = b3 ? a[2] : __int_as_float(u0);
    float A1 = b3 ? __int_as_float(t1) : a[1];
    float A3 = b3 ? a[3] : __int_as_float(u1);
    a[0] = A0; a[1] = A1; a[2] = A2; a[3] = A3;
  }
}

__global__ void lstm_zero_ws(u32* __restrict__ p) {
  int i = blockIdx.x * 256 + threadIdx.x;
  if (i < ZERO_U32) p[i] = 0;
}

__global__ void lstm_xpack(const float* __restrict__ x, u32* __restrict__ xpk) {
  long i = ((long)blockIdx.x * 256 + threadIdx.x) * 4;
  if (i >= (long)XEL) return;
  f32x4 v = *(const f32x4*)(x + i);
  u32x4 o;
#pragma unroll
  for (int e = 0; e < 4; ++e) o[e] = packbf(v[e] * PKEEP);
  *(u32x4*)(xpk + i) = o;
}

// ============ x-role: v16 verbatim ==========================================
__device__ __forceinline__ void x_role(
    const float* __restrict__ x, const float* __restrict__ W,
    u32* __restrict__ Gxb, int* __restrict__ xf, u32* smem) {
  const int bx = blockIdx.x - NH;
  const int m = bx >> 4, n = bx & 15;
  const int tid = threadIdx.x, lane = tid & 63, wave = tid >> 6;
  const int n16 = lane & 15, kgrp = lane >> 4;

  const int ghc_w = n * 16 + wave * 4 + (n16 & 3);
  const int grow = (n16 >> 2) * HID + ghc_w;
  s16x8 BWh[8], BWl[8];
#pragma unroll
  for (int ks = 0; ks < 8; ++ks) {
    const int base = grow * DIM + ks * 32 + kgrp * 8;
#pragma unroll
    for (int e = 0; e < 8; ++e) {
      float wv = W[base + e];
      u16 wh = f2bf_rne(wv);
      BWh[ks][e] = (short)wh;
      BWl[ks][e] = (short)f2bf_rne(wv - bf2f(wh));
    }
  }
  const bool b2 = (lane >> 2) & 1, b3 = (lane >> 3) & 1;
  const int row_l = kgrp * 4 + (n16 >> 2);
  const int gb = m * RPG + row_l;
  int* flagp = xf + (m * 16 + n) * 16;

  {
    const int R = wave * 4;
    const long tb = (long)(m * RPG) * DIM;
#pragma unroll
    for (int r = 0; r < 4; ++r) {
      const long src = tb + (long)(R + r) * DIM + 4 * (lane ^ ((R + r) & 15));
      gload_lds16((const u32*)x + src, smem + (R + r) * HID);
    }
  }

  for (int t = 0; t < T_STEPS; ++t) {
    const int par = t & 1;
    asm volatile("s_waitcnt vmcnt(0)" ::: "memory");
    __builtin_amdgcn_sched_barrier(0);
    __syncthreads();

    const int swz = n16 << 4;
    const char* xs = (const char*)smem + par * (RPG * HID * 4);
    f32x4 ax = {0.f, 0.f, 0.f, 0.f};
#pragma unroll
    for (int ks = 0; ks < 8; ++ks) {
      const int bb = n16 * 1024 + (kgrp * 8 + ks * 32) * 4;
      f32x4 f0 = *(const f32x4*)(xs + (bb ^ swz));
      f32x4 f1 = *(const f32x4*)(xs + ((bb + 16) ^ swz));
      s16x8 Xh, Xl;
#pragma unroll
      for (int e = 0; e < 8; ++e) {
        float v = (e < 4 ? f0[e] : f1[e - 4]) * PKEEP;
        unsigned hb = __float_as_uint(v) & 0xFFFF0000u;
        Xh[e] = (short)(hb >> 16);
        Xl[e] = (short)(u16)(__float_as_uint(v - __uint_as_float(hb)) >> 16);
      }
      ax = __builtin_amdgcn_mfma_f32_16x16x32_bf16(Xh, BWh[ks], ax, 0, 0, 0);
      ax = __builtin_amdgcn_mfma_f32_16x16x32_bf16(Xl, BWh[ks], ax, 0, 0, 0);
      ax = __builtin_amdgcn_mfma_f32_16x16x32_bf16(Xh, BWl[ks], ax, 0, 0, 0);
    }

    f32x4 g4 = ax;
    xpose4(g4, b2, b3);
    u32x2 pv;
    pv[0] = ((u32)f2bf_rne(g4[0]) << 16) | (u32)f2bf_rne(g4[1]);  // i | f
    pv[1] = ((u32)f2bf_rne(g4[2]) << 16) | (u32)f2bf_rne(g4[3]);  // g | o
    dev_st_u32x2(Gxb + ((long)(t * BATCH + gb)) * 512 + ghc_w * 2, pv);

    asm volatile("s_waitcnt vmcnt(0)" ::: "memory");
    __syncthreads();
    if (tid == 0) coh_st_i32(flagp, t + 1);
    if (t + 1 < T_STEPS) {
      const int R = wave * 4;
      const long tb = (long)(t + 1) * (BATCH * DIM) + (long)(m * RPG) * DIM;
#pragma unroll
      for (int r = 0; r < 4; ++r) {
        const long src = tb + (long)(R + r) * DIM + 4 * (lane ^ ((R + r) & 15));
        gload_lds16((const u32*)x + src, smem + (par ^ 1) * (RPG * HID) + (R + r) * HID);
      }
    }
  }
}

// ============ h-role: v16 + no-bottom-drain + 3-chain MFMA ==================
__device__ __forceinline__ void h_role(
    const int* __restrict__ lens, const float* __restrict__ U,
    const float* __restrict__ bih, const float* __restrict__ bhh,
    float* __restrict__ out, u32* __restrict__ hbuf,
    const u32* __restrict__ Gxb, const int* __restrict__ xf, u32* smem) {
  const int wg = blockIdx.x, tid = threadIdx.x;
  const int m = wg >> 4, n = wg & 15;
  const int lane = tid & 63, wave = tid >> 6;
  const int n16 = lane & 15, kgrp = lane >> 4;

  const int ghc_w = n * 16 + wave * 4 + (n16 & 3);
  const int grow = (n16 >> 2) * HID + ghc_w;
  s16x8 BUh[8], BUl[8];
#pragma unroll
  for (int ks = 0; ks < 8; ++ks) {
    const int base = grow * DIM + ks * 32 + kgrp * 8;
#pragma unroll
    for (int e = 0; e < 8; ++e) {
      float uv = U[base + e];
      u16 uh = f2bf_rne(uv);
      BUh[ks][e] = (short)uh;
      BUl[ks][e] = (short)f2bf_rne(uv - bf2f(uh));
    }
  }

  const bool b2 = (lane >> 2) & 1, b3 = (lane >> 3) & 1;
  const int row_l = kgrp * 4 + (n16 >> 2);
  const int gb = m * RPG + row_l;
  const float bi  = bih[0 * HID + ghc_w] + bhh[0 * HID + ghc_w];
  const float bfo = bih[1 * HID + ghc_w] + bhh[1 * HID + ghc_w];
  const float bg  = bih[2 * HID + ghc_w] + bhh[2 * HID + ghc_w];
  const float bo  = bih[3 * HID + ghc_w] + bhh[3 * HID + ghc_w];
  const int len = lens[gb];
  float hreg = 0.0f, creg = 0.0f;

  const int rh = tid >> 7, p = tid & 127;
  const int* flagp = xf + (m * 16 + n) * 16;
  int f = 0;

  for (int t = 0; t < T_STEPS; ++t) {
    const int par = t & 1;

    // ---- Gx flag gate (prefetched before last step's stores; vmcnt-FIFO
    //      means reading f waits only on its own load, not store acks)
    if (f < t + 1) {
      do {
        f = coh_ld_i32(flagp);
        asm volatile("s_waitcnt vmcnt(0)" ::: "memory");
        __builtin_amdgcn_sched_barrier(0);
      } while (f < t + 1);
    }
    u32x2 gxu = coh_ld_u32x2(Gxb + ((long)(t * BATCH + gb)) * 512 + ghc_w * 2);

    // ---- poll h pair-lines (v8 verbatim); first vmcnt(0) also drains the
    //      previous step's publish/out stores IN PARALLEL with poll RT
    u32x4 P[8];
    {
      const u32* rb = hbuf + par * PLANE_U32 + m * REGION_U32 + rh * (8 * 512) + p * 4;
      for (;;) {
#pragma unroll
        for (int j = 0; j < 8; ++j)
          asm volatile("global_load_dwordx4 %0, %1, off sc0 sc1"
                       : "=v"(P[j]) : "v"(rb + j * 512) : "memory");
        asm volatile("s_waitcnt vmcnt(0)" ::: "memory");
        if (t == 0) break;
        bool stale = false;
#pragma unroll
        for (int j = 0; j < 8; ++j)
          stale |= (P[j][1] != (u32)t) || (P[j][3] != (u32)t);
        if (!__any(stale)) break;
      }
    }
    __builtin_amdgcn_sched_barrier(0);

    // ---- stage h (v8 verbatim, conflict-free)
    char* hs = (char*)smem + par * (RPG * HID * 4);
#pragma unroll
    for (int j = 0; j < 8; ++j) {
      const int row = rh * 8 + j;
      const int byte = (row * 1024 + p * 8) ^ (row << 4);
      u32x2 v = {P[j][0], P[j][2]};
      *(u32x2*)(hs + byte) = v;
    }
    __syncthreads();

    // ---- h-only gate GEMM: 24 MFMAs in 3 independent 8-deep chains
    const int swz = n16 << 4;
    f32x4 aA = {0.f, 0.f, 0.f, 0.f}, aB = {0.f, 0.f, 0.f, 0.f}, aC = {0.f, 0.f, 0.f, 0.f};
#pragma unroll
    for (int ks = 0; ks < 8; ++ks) {
      const int bb = n16 * 1024 + (kgrp * 8 + ks * 32) * 4;
      u32x4 h0 = *(const u32x4*)(hs + (bb ^ swz));
      u32x4 h1 = *(const u32x4*)(hs + ((bb + 16) ^ swz));
      s16x8 Hh, Hl;
      unpack8(h0, h1, Hh, Hl);
      aA = __builtin_amdgcn_mfma_f32_16x16x32_bf16(Hh, BUh[ks], aA, 0, 0, 0);
      aB = __builtin_amdgcn_mfma_f32_16x16x32_bf16(Hl, BUh[ks], aB, 0, 0, 0);
      aC = __builtin_amdgcn_mfma_f32_16x16x32_bf16(Hh, BUl[ks], aC, 0, 0, 0);
    }

    // ---- gather + cell (v14/v16 verbatim numerics)
    f32x4 g4 = (aA + aB) + aC;
    xpose4(g4, b2, b3);
    float gi = g4[0] + __uint_as_float(gxu[0] & 0xFFFF0000u) + bi;
    float gf = g4[1] + __uint_as_float(gxu[0] << 16)          + bfo;
    float gg = g4[2] + __uint_as_float(gxu[1] & 0xFFFF0000u) + bg;
    float go = g4[3] + __uint_as_float(gxu[1] << 16)          + bo;
    float it = sigm(gi), ft = sigm(gf), ot = sigm(go);
    float gt = tanh_f(gg);
    float cnew = ft * creg + it * gt;
    float hnew = ot * tanh_f(cnew);
    const bool act = (t < len);
    if (act) { creg = cnew; hreg = hnew; }

    // ---- flag prefetch FIRST (oldest outstanding -> loop-top read waits
    //      only on it), then publish, then out store. No bottom drain.
    if (t + 1 < T_STEPS) f = coh_ld_i32(flagp);
    {
      u32x2 pv = {packbf(hreg * PKEEP), (u32)(t + 1)};
      dev_st_u32x2(hbuf + (par ^ 1) * PLANE_U32 + m * REGION_U32 + row_l * 512 + ghc_w * 2, pv);
    }
    out[(long)t * (BATCH * HID) + gb * HID + ghc_w] = act ? hnew : 0.0f;
  }

  out[(long)T_STEPS * (BATCH * HID) + gb * HID + ghc_w] = hreg;
  out[(long)T_STEPS * (BATCH * HID) + BATCH * HID + gb * HID + ghc_w] = creg;
}

__global__ __launch_bounds__(256, 1) void lstm_fused_v17(
    const float* __restrict__ x, const int* __restrict__ lens,
    const float* __restrict__ W, const float* __restrict__ U,
    const float* __restrict__ bih, const float* __restrict__ bhh,
    float* __restrict__ out, u32* __restrict__ hbuf,
    u32* __restrict__ Gxb, int* __restrict__ xf) {
  __shared__ u32 smem[2 * RPG * HID];  // 32KB, role-dependent
  if (blockIdx.x < NH) h_role(lens, U, bih, bhh, out, hbuf, Gxb, xf, smem);
  else                 x_role(x, W, Gxb, xf, smem);
}

// ================= v8 fallback (proven), verbatim ============================
template <int MODE>
__device__ __forceinline__ void recur_body8(
    const float* __restrict__ x, const int* __restrict__ lens,
    const float* __restrict__ W, const float* __restrict__ U,
    const float* __restrict__ bih, const float* __restrict__ bhh,
    float* __restrict__ out, u32* __restrict__ hbuf, const u32* __restrict__ xpk) {
  const int wg = blockIdx.x, tid = threadIdx.x;
  const int m = wg >> 4, n = wg & 15;
  const int lane = tid & 63, wave = tid >> 6;
  const int n16 = lane & 15, kgrp = lane >> 4;

  const int ghc_w = n * 16 + wave * 4 + (n16 & 3);
  const int grow = (n16 >> 2) * HID + ghc_w;
  s16x8 BUh[8], BUl[8], BWh[8], BWl[8];
#pragma unroll
  for (int ks = 0; ks < 8; ++ks) {
    const int base = grow * DIM + ks * 32 + kgrp * 8;
#pragma unroll
    for (int e = 0; e < 8; ++e) {
      float uv = U[base + e];
      u16 uh = f2bf_rne(uv);
      BUh[ks][e] = (short)uh;
      BUl[ks][e] = (short)f2bf_rne(uv - bf2f(uh));
      float wv = W[base + e];
      u16 wh = f2bf_rne(wv);
      BWh[ks][e] = (short)wh;
      BWl[ks][e] = (short)f2bf_rne(wv - bf2f(wh));
    }
  }

  const bool b2 = (lane >> 2) & 1, b3 = (lane >> 3) & 1;
  const int row_l = kgrp * 4 + (n16 >> 2);
  const int gb = m * RPG + row_l;
  const float bi  = bih[0 * HID + ghc_w] + bhh[0 * HID + ghc_w];
  const float bfo = bih[1 * HID + ghc_w] + bhh[1 * HID + ghc_w];
  const float bg  = bih[2 * HID + ghc_w] + bhh[2 * HID + ghc_w];
  const float bo  = bih[3 * HID + ghc_w] + bhh[3 * HID + ghc_w];
  const int len = lens[gb];
  float hreg = 0.0f, creg = 0.0f;

  const int rh = tid >> 7, p = tid & 127;

  __shared__ u32 hstage[2][RPG * HID];
  __shared__ u32 xstage[2][RPG * HID];

  {
    const int R = wave * 4;
    const long tb = (long)(m * RPG) * DIM;
#pragma unroll
    for (int r = 0; r < 4; ++r) {
      const long src = tb + (long)(R + r) * DIM + 4 * (lane ^ ((R + r) & 15));
      if constexpr (MODE == 0) gload_lds16(xpk + src, &xstage[0][(R + r) * HID]);
      else                     gload_lds16((const u32*)x + src, &xstage[0][(R + r) * HID]);
    }
  }

  for (int t = 0; t < T_STEPS; ++t) {
    const int par = t & 1;
    u32x4 P[8];
    {
      const u32* rb = hbuf + par * PLANE_U32 + m * REGION_U32 + rh * (8 * 512) + p * 4;
      for (;;) {
#pragma unroll
        for (int j = 0; j < 8; ++j)
          asm volatile("global_load_dwordx4 %0, %1, off sc0 sc1"
                       : "=v"(P[j]) : "v"(rb + j * 512) : "memory");
        asm volatile("s_waitcnt vmcnt(0)" ::: "memory");
        if (t == 0) break;
        bool stale = false;
#pragma unroll
        for (int j = 0; j < 8; ++j)
          stale |= (P[j][1] != (u32)t) || (P[j][3] != (u32)t);
        if (!__any(stale)) break;
      }
    }
    __builtin_amdgcn_sched_barrier(0);

#pragma unroll
    for (int j = 0; j < 8; ++j) {
      const int row = rh * 8 + j;
      const int byte = (row * 1024 + p * 8) ^ (row << 4);
      u32x2 v = {P[j][0], P[j][2]};
      *(u32x2*)((char*)hstage[par] + byte) = v;
    }
    __syncthreads();

    const int swz = n16 << 4;
    f32x4 ah = {0.f, 0.f, 0.f, 0.f}, ax = {0.f, 0.f, 0.f, 0.f};
#pragma unroll
    for (int ks = 0; ks < 8; ++ks) {
      const int bb = n16 * 1024 + (kgrp * 8 + ks * 32) * 4;
      u32x4 h0 = *(const u32x4*)((const char*)hstage[par] + (bb ^ swz));
      u32x4 h1 = *(const u32x4*)((const char*)hstage[par] + ((bb + 16) ^ swz));
      s16x8 Hh, Hl, Xh, Xl;
      unpack8(h0, h1, Hh, Hl);
      if constexpr (MODE == 0) {
        u32x4 x0 = *(const u32x4*)((const char*)xstage[par] + (bb ^ swz));
        u32x4 x1 = *(const u32x4*)((const char*)xstage[par] + ((bb + 16) ^ swz));
        unpack8(x0, x1, Xh, Xl);
      } else {
        f32x4 f0 = *(const f32x4*)((const char*)xstage[par] + (bb ^ swz));
        f32x4 f1 = *(const f32x4*)((const char*)xstage[par] + ((bb + 16) ^ swz));
#pragma unroll
        for (int e = 0; e < 8; ++e) {
          float v = (e < 4 ? f0[e] : f1[e - 4]) * PKEEP;
          unsigned hb = __float_as_uint(v) & 0xFFFF0000u;
          Xh[e] = (short)(hb >> 16);
          Xl[e] = (short)(u16)(__float_as_uint(v - __uint_as_float(hb)) >> 16);
        }
      }
      ah = __builtin_amdgcn_mfma_f32_16x16x32_bf16(Hh, BUh[ks], ah, 0, 0, 0);
      ax = __builtin_amdgcn_mfma_f32_16x16x32_bf16(Xh, BWh[ks], ax, 0, 0, 0);
      ah = __builtin_amdgcn_mfma_f32_16x16x32_bf16(Hl, BUh[ks], ah, 0, 0, 0);
      ax = __builtin_amdgcn_mfma_f32_16x16x32_bf16(Xl, BWh[ks], ax, 0, 0, 0);
      ah = __builtin_amdgcn_mfma_f32_16x16x32_bf16(Hh, BUl[ks], ah, 0, 0, 0);
      ax = __builtin_amdgcn_mfma_f32_16x16x32_bf16(Xh, BWl[ks], ax, 0, 0, 0);
    }

    f32x4 g4 = ah + ax;
    xpose4(g4, b2, b3);

    float gi = g4[0] + bi, gf = g4[1] + bfo, gg = g4[2] + bg, go = g4[3] + bo;
    float it = sigm(gi), ft = sigm(gf), ot = sigm(go);
    float gt = tanh_f(gg);
    float cnew = ft * creg + it * gt;
    float hnew = ot * tanh_f(cnew);
    const bool act = (t < len);
    if (act) { creg = cnew; hreg = hnew; }
    {
      u32x2 pv = {packbf(hreg * PKEEP), (u32)(t + 1)};
      dev_st_u32x2(hbuf + (par ^ 1) * PLANE_U32 + m * REGION_U32 + row_l * 512 + ghc_w * 2, pv);
    }

    if (t + 1 < T_STEPS) {
      const int R = wave * 4;
      const long tb = (long)(t + 1) * (BATCH * DIM) + (long)(m * RPG) * DIM;
#pragma unroll
      for (int r = 0; r < 4; ++r) {
        const long src = tb + (long)(R + r) * DIM + 4 * (lane ^ ((R + r) & 15));
        if constexpr (MODE == 0) gload_lds16(xpk + src, &xstage[par ^ 1][(R + r) * HID]);
        else                     gload_lds16((const u32*)x + src, &xstage[par ^ 1][(R + r) * HID]);
      }
    }
    out[(long)t * (BATCH * HID) + gb * HID + ghc_w] = act ? hnew : 0.0f;

    asm volatile("s_waitcnt vmcnt(0)" ::: "memory");
    __builtin_amdgcn_sched_barrier(0);
  }

  out[(long)T_STEPS * (BATCH * HID) + gb * HID + ghc_w] = hreg;
  out[(long)T_STEPS * (BATCH * HID) + BATCH * HID + gb * HID + ghc_w] = creg;
}

#define RECUR_PARAMS                                                          \
  const float* __restrict__ x, const int* __restrict__ lens,                  \
  const float* __restrict__ W, const float* __restrict__ U,                   \
  const float* __restrict__ bih, const float* __restrict__ bhh,               \
  float* __restrict__ out, u32* __restrict__ hbuf, const u32* __restrict__ xpk
#define RECUR_ARGS x, lens, W, U, bih, bhh, out, hbuf, xpk

__global__ __launch_bounds__(256, 1) void lstm_recur_v8_xpk(RECUR_PARAMS) { recur_body8<0>(RECUR_ARGS); }
__global__ __launch_bounds__(256, 1) void lstm_recur_v8_dir(RECUR_PARAMS) { recur_body8<1>(RECUR_ARGS); }

extern "C" void kernel_launch(void* const* d_in, const int* in_sizes, int n_in,
                              void* d_out, int out_size, void* d_ws, size_t ws_size,
                              hipStream_t stream) {
  const float* x   = (const float*)d_in[0];
  const int*   len = (const int*)d_in[1];
  const float* W   = (const float*)d_in[2];
  const float* U   = (const float*)d_in[3];
  const float* bih = (const float*)d_in[4];
  const float* bhh = (const float*)d_in[5];
  float* out = (float*)d_out;
  char*  ws  = (char*)d_ws;
  int* xf   = (int*)(ws + XF_OFF);
  u32* hbuf = (u32*)(ws + HBUF_OFF);
  char* big = ws + BIG_OFF;

  lstm_zero_ws<<<dim3((ZERO_U32 + 255) / 256), dim3(256), 0, stream>>>((u32*)ws);

  const size_t need_gx = (size_t)BIG_OFF + (size_t)T_STEPS * BATCH * 512 * 4;  // ~257MB
  const size_t need_xp = (size_t)BIG_OFF + (size_t)XEL * 4;                    // ~129MB
  if (ws_size >= need_gx) {
    u32* Gxb = (u32*)big;
    lstm_fused_v17<<<dim3(NH + NX), dim3(256), 0, stream>>>(x, len, W, U, bih, bhh,
                                                            out, hbuf, Gxb, xf);
  } else if (ws_size >= need_xp) {
    u32* xpk = (u32*)big;
    lstm_xpack<<<dim3(32768), dim3(256), 0, stream>>>(x, xpk);
    lstm_recur_v8_xpk<<<dim3(64), dim3(256), 0, stream>>>(x, len, W, U, bih, bhh, out, hbuf, xpk);
  } else {
    lstm_recur_v8_dir<<<dim3(64), dim3(256), 0, stream>>>(x, len, W, U, bih, bhh, out, hbuf, nullptr);
  }
}

// Round 18
// 4503.485 us; speedup vs baseline: 1.0801x; 1.0801x over previous
//
#include <hip/hip_runtime.h>

// LSTM v18 for MI355X.
// v16 VERBATIM (proven 4.51ms) with exactly ONE change: the h-role 24-MFMA
// dependent chain is split into 3 independent 8-deep chains (aA/aB/aC).
// Bottom drain and flag-prefetch placement restored to v16 (v17's removal
// regressed: store-acks must drain in the loop-bottom slack, not inside the
// discovery window). Fallback ws<257MB: v8 xpk (proven 5.19ms).

#define T_STEPS 2048
#define BATCH   64
#define DIM     256
#define HID     256
#define PKEEP   0.7f
#define RPG     16
#define REGION_U32 (RPG * HID * 2)       // 8192 u32
#define PLANE_U32  (4 * REGION_U32)      // 32768 u32 (128KB)
#define XEL     (T_STEPS * BATCH * DIM)
#define NH      64
#define NX      64

typedef __attribute__((ext_vector_type(8))) short s16x8;
typedef __attribute__((ext_vector_type(4))) float f32x4;
typedef __attribute__((ext_vector_type(4))) unsigned int u32x4;
typedef __attribute__((ext_vector_type(2))) unsigned int u32x2;
typedef unsigned int u32;
typedef unsigned short u16;

#define XF_OFF   4096                    // 64 flags, 64B apart
#define HBUF_OFF 16384
#define BIG_OFF  (1 << 20)
#define ZERO_U32 ((HBUF_OFF + 2 * PLANE_U32 * 4) / 4)

#define HISEL 0x07060302u
#define LOSEL 0x05040100u

__device__ __forceinline__ u16 f2bf_rne(float f) {
  unsigned x = __float_as_uint(f);
  return (u16)((x + 0x7fffu + ((x >> 16) & 1u)) >> 16);
}
__device__ __forceinline__ float bf2f(u16 u) { return __uint_as_float(((unsigned)u) << 16); }
__device__ __forceinline__ float sigm(float v) { return 1.0f / (1.0f + __expf(-v)); }
__device__ __forceinline__ float tanh_f(float v) {
  float e = __expf(-2.0f * fabsf(v));
  float r = (1.0f - e) / (1.0f + e);
  return v < 0.0f ? -r : r;
}
__device__ __forceinline__ u32 packbf(float v) {
  u32 uh = __float_as_uint(v) & 0xFFFF0000u;
  u32 lo = (u32)f2bf_rne(v - __uint_as_float(uh));
  return uh | lo;
}
__device__ __forceinline__ void dev_st_u32x2(u32* p, u32x2 v) {
  asm volatile("global_store_dwordx2 %0, %1, off sc0 sc1" :: "v"(p), "v"(v) : "memory");
}
__device__ __forceinline__ void coh_st_i32(int* p, int v) {
  asm volatile("global_store_dword %0, %1, off sc0 sc1" :: "v"(p), "v"(v) : "memory");
}
__device__ __forceinline__ int coh_ld_i32(const int* p) {
  int v;
  asm volatile("global_load_dword %0, %1, off sc0 sc1" : "=v"(v) : "v"(p) : "memory");
  return v;
}
__device__ __forceinline__ u32x2 coh_ld_u32x2(const u32* p) {
  u32x2 v;
  asm volatile("global_load_dwordx2 %0, %1, off sc0 sc1" : "=v"(v) : "v"(p) : "memory");
  return v;
}
__device__ __forceinline__ void gload_lds16(const u32* g, u32* lds) {
  __builtin_amdgcn_global_load_lds(
      (const __attribute__((address_space(1))) u32*)g,
      (__attribute__((address_space(3))) u32*)lds, 16, 0, 0);
}
__device__ __forceinline__ void unpack8(u32x4 a, u32x4 b, s16x8& hi, s16x8& lo) {
  u32x4 H, L;
  H[0] = __builtin_amdgcn_perm(a[1], a[0], HISEL);
  H[1] = __builtin_amdgcn_perm(a[3], a[2], HISEL);
  H[2] = __builtin_amdgcn_perm(b[1], b[0], HISEL);
  H[3] = __builtin_amdgcn_perm(b[3], b[2], HISEL);
  L[0] = __builtin_amdgcn_perm(a[1], a[0], LOSEL);
  L[1] = __builtin_amdgcn_perm(a[3], a[2], LOSEL);
  L[2] = __builtin_amdgcn_perm(b[1], b[0], LOSEL);
  L[3] = __builtin_amdgcn_perm(b[3], b[2], LOSEL);
  hi = __builtin_bit_cast(s16x8, H);
  lo = __builtin_bit_cast(s16x8, L);
}
// 4x4 reg<->lane-bit transpose (proven v8)
__device__ __forceinline__ void xpose4(f32x4& a, bool b2, bool b3) {
  {
    int t0 = __builtin_amdgcn_ds_swizzle(__float_as_int(a[1]), 0x101F);
    int u0 = __builtin_amdgcn_ds_swizzle(__float_as_int(a[0]), 0x101F);
    int t1 = __builtin_amdgcn_ds_swizzle(__float_as_int(a[3]), 0x101F);
    int u1 = __builtin_amdgcn_ds_swizzle(__float_as_int(a[2]), 0x101F);
    float A0 = b2 ? __int_as_float(t0) : a[0];
    float A1 = b2 ? a[1] : __int_as_float(u0);
    float A2 = b2 ? __int_as_float(t1) : a[2];
    float A3 = b2 ? a[3] : __int_as_float(u1);
    a[0] = A0; a[1] = A1; a[2] = A2; a[3] = A3;
  }
  {
    int t0 = __builtin_amdgcn_ds_swizzle(__float_as_int(a[2]), 0x201F);
    int u0 = __builtin_amdgcn_ds_swizzle(__float_as_int(a[0]), 0x201F);
    int t1 = __builtin_amdgcn_ds_swizzle(__float_as_int(a[3]), 0x201F);
    int u1 = __builtin_amdgcn_ds_swizzle(__float_as_int(a[1]), 0x201F);
    float A0 = b3 ? __int_as_float(t0) : a[0];
    float A2 = b3 ? a[2] : __int_as_float(u0);
    float A1 = b3 ? __int_as_float(t1) : a[1];
    float A3 = b3 ? a[3] : __int_as_float(u1);
    a[0] = A0; a[1] = A1; a[2] = A2; a[3] = A3;
  }
}

__global__ void lstm_zero_ws(u32* __restrict__ p) {
  int i = blockIdx.x * 256 + threadIdx.x;
  if (i < ZERO_U32) p[i] = 0;
}

__global__ void lstm_xpack(const float* __restrict__ x, u32* __restrict__ xpk) {
  long i = ((long)blockIdx.x * 256 + threadIdx.x) * 4;
  if (i >= (long)XEL) return;
  f32x4 v = *(const f32x4*)(x + i);
  u32x4 o;
#pragma unroll
  for (int e = 0; e < 4; ++e) o[e] = packbf(v[e] * PKEEP);
  *(u32x4*)(xpk + i) = o;
}

// ============ x-role: v16 verbatim ==========================================
__device__ __forceinline__ void x_role(
    const float* __restrict__ x, const float* __restrict__ W,
    u32* __restrict__ Gxb, int* __restrict__ xf, u32* smem) {
  const int bx = blockIdx.x - NH;
  const int m = bx >> 4, n = bx & 15;
  const int tid = threadIdx.x, lane = tid & 63, wave = tid >> 6;
  const int n16 = lane & 15, kgrp = lane >> 4;

  const int ghc_w = n * 16 + wave * 4 + (n16 & 3);
  const int grow = (n16 >> 2) * HID + ghc_w;
  s16x8 BWh[8], BWl[8];
#pragma unroll
  for (int ks = 0; ks < 8; ++ks) {
    const int base = grow * DIM + ks * 32 + kgrp * 8;
#pragma unroll
    for (int e = 0; e < 8; ++e) {
      float wv = W[base + e];
      u16 wh = f2bf_rne(wv);
      BWh[ks][e] = (short)wh;
      BWl[ks][e] = (short)f2bf_rne(wv - bf2f(wh));
    }
  }
  const bool b2 = (lane >> 2) & 1, b3 = (lane >> 3) & 1;
  const int row_l = kgrp * 4 + (n16 >> 2);
  const int gb = m * RPG + row_l;
  int* flagp = xf + (m * 16 + n) * 16;

  {
    const int R = wave * 4;
    const long tb = (long)(m * RPG) * DIM;
#pragma unroll
    for (int r = 0; r < 4; ++r) {
      const long src = tb + (long)(R + r) * DIM + 4 * (lane ^ ((R + r) & 15));
      gload_lds16((const u32*)x + src, smem + (R + r) * HID);
    }
  }

  for (int t = 0; t < T_STEPS; ++t) {
    const int par = t & 1;
    asm volatile("s_waitcnt vmcnt(0)" ::: "memory");
    __builtin_amdgcn_sched_barrier(0);
    __syncthreads();

    const int swz = n16 << 4;
    const char* xs = (const char*)smem + par * (RPG * HID * 4);
    f32x4 ax = {0.f, 0.f, 0.f, 0.f};
#pragma unroll
    for (int ks = 0; ks < 8; ++ks) {
      const int bb = n16 * 1024 + (kgrp * 8 + ks * 32) * 4;
      f32x4 f0 = *(const f32x4*)(xs + (bb ^ swz));
      f32x4 f1 = *(const f32x4*)(xs + ((bb + 16) ^ swz));
      s16x8 Xh, Xl;
#pragma unroll
      for (int e = 0; e < 8; ++e) {
        float v = (e < 4 ? f0[e] : f1[e - 4]) * PKEEP;
        unsigned hb = __float_as_uint(v) & 0xFFFF0000u;
        Xh[e] = (short)(hb >> 16);
        Xl[e] = (short)(u16)(__float_as_uint(v - __uint_as_float(hb)) >> 16);
      }
      ax = __builtin_amdgcn_mfma_f32_16x16x32_bf16(Xh, BWh[ks], ax, 0, 0, 0);
      ax = __builtin_amdgcn_mfma_f32_16x16x32_bf16(Xl, BWh[ks], ax, 0, 0, 0);
      ax = __builtin_amdgcn_mfma_f32_16x16x32_bf16(Xh, BWl[ks], ax, 0, 0, 0);
    }

    f32x4 g4 = ax;
    xpose4(g4, b2, b3);
    u32x2 pv;
    pv[0] = ((u32)f2bf_rne(g4[0]) << 16) | (u32)f2bf_rne(g4[1]);  // i | f
    pv[1] = ((u32)f2bf_rne(g4[2]) << 16) | (u32)f2bf_rne(g4[3]);  // g | o
    dev_st_u32x2(Gxb + ((long)(t * BATCH + gb)) * 512 + ghc_w * 2, pv);

    asm volatile("s_waitcnt vmcnt(0)" ::: "memory");
    __syncthreads();
    if (tid == 0) coh_st_i32(flagp, t + 1);
    if (t + 1 < T_STEPS) {
      const int R = wave * 4;
      const long tb = (long)(t + 1) * (BATCH * DIM) + (long)(m * RPG) * DIM;
#pragma unroll
      for (int r = 0; r < 4; ++r) {
        const long src = tb + (long)(R + r) * DIM + 4 * (lane ^ ((R + r) & 15));
        gload_lds16((const u32*)x + src, smem + (par ^ 1) * (RPG * HID) + (R + r) * HID);
      }
    }
  }
}

// ============ h-role: v16 verbatim + 3-chain MFMA (ONLY change) =============
__device__ __forceinline__ void h_role(
    const int* __restrict__ lens, const float* __restrict__ U,
    const float* __restrict__ bih, const float* __restrict__ bhh,
    float* __restrict__ out, u32* __restrict__ hbuf,
    const u32* __restrict__ Gxb, const int* __restrict__ xf, u32* smem) {
  const int wg = blockIdx.x, tid = threadIdx.x;
  const int m = wg >> 4, n = wg & 15;
  const int lane = tid & 63, wave = tid >> 6;
  const int n16 = lane & 15, kgrp = lane >> 4;

  const int ghc_w = n * 16 + wave * 4 + (n16 & 3);
  const int grow = (n16 >> 2) * HID + ghc_w;
  s16x8 BUh[8], BUl[8];
#pragma unroll
  for (int ks = 0; ks < 8; ++ks) {
    const int base = grow * DIM + ks * 32 + kgrp * 8;
#pragma unroll
    for (int e = 0; e < 8; ++e) {
      float uv = U[base + e];
      u16 uh = f2bf_rne(uv);
      BUh[ks][e] = (short)uh;
      BUl[ks][e] = (short)f2bf_rne(uv - bf2f(uh));
    }
  }

  const bool b2 = (lane >> 2) & 1, b3 = (lane >> 3) & 1;
  const int row_l = kgrp * 4 + (n16 >> 2);
  const int gb = m * RPG + row_l;
  const float bi  = bih[0 * HID + ghc_w] + bhh[0 * HID + ghc_w];
  const float bfo = bih[1 * HID + ghc_w] + bhh[1 * HID + ghc_w];
  const float bg  = bih[2 * HID + ghc_w] + bhh[2 * HID + ghc_w];
  const float bo  = bih[3 * HID + ghc_w] + bhh[3 * HID + ghc_w];
  const int len = lens[gb];
  float hreg = 0.0f, creg = 0.0f;

  const int rh = tid >> 7, p = tid & 127;
  const int* flagp = xf + (m * 16 + n) * 16;
  int f = 0;

  for (int t = 0; t < T_STEPS; ++t) {
    const int par = t & 1;

    // ---- Gx flag gate (prefetched; spins only during warmup) — v16 verbatim
    if (f < t + 1) {
      do {
        f = coh_ld_i32(flagp);
        asm volatile("s_waitcnt vmcnt(0)" ::: "memory");
        __builtin_amdgcn_sched_barrier(0);
      } while (f < t + 1);
    }
    u32x2 gxu = coh_ld_u32x2(Gxb + ((long)(t * BATCH + gb)) * 512 + ghc_w * 2);

    // ---- poll h pair-lines (v16 verbatim)
    u32x4 P[8];
    {
      const u32* rb = hbuf + par * PLANE_U32 + m * REGION_U32 + rh * (8 * 512) + p * 4;
      for (;;) {
#pragma unroll
        for (int j = 0; j < 8; ++j)
          asm volatile("global_load_dwordx4 %0, %1, off sc0 sc1"
                       : "=v"(P[j]) : "v"(rb + j * 512) : "memory");
        asm volatile("s_waitcnt vmcnt(0)" ::: "memory");
        if (t == 0) break;
        bool stale = false;
#pragma unroll
        for (int j = 0; j < 8; ++j)
          stale |= (P[j][1] != (u32)t) || (P[j][3] != (u32)t);
        if (!__any(stale)) break;
      }
    }
    __builtin_amdgcn_sched_barrier(0);

    // ---- stage h (v16 verbatim, conflict-free)
    char* hs = (char*)smem + par * (RPG * HID * 4);
#pragma unroll
    for (int j = 0; j < 8; ++j) {
      const int row = rh * 8 + j;
      const int byte = (row * 1024 + p * 8) ^ (row << 4);
      u32x2 v = {P[j][0], P[j][2]};
      *(u32x2*)(hs + byte) = v;
    }
    __syncthreads();

    // ---- h-only gate GEMM: 24 MFMAs in 3 independent 8-deep chains (ONLY change)
    const int swz = n16 << 4;
    f32x4 aA = {0.f, 0.f, 0.f, 0.f}, aB = {0.f, 0.f, 0.f, 0.f}, aC = {0.f, 0.f, 0.f, 0.f};
#pragma unroll
    for (int ks = 0; ks < 8; ++ks) {
      const int bb = n16 * 1024 + (kgrp * 8 + ks * 32) * 4;
      u32x4 h0 = *(const u32x4*)(hs + (bb ^ swz));
      u32x4 h1 = *(const u32x4*)(hs + ((bb + 16) ^ swz));
      s16x8 Hh, Hl;
      unpack8(h0, h1, Hh, Hl);
      aA = __builtin_amdgcn_mfma_f32_16x16x32_bf16(Hh, BUh[ks], aA, 0, 0, 0);
      aB = __builtin_amdgcn_mfma_f32_16x16x32_bf16(Hl, BUh[ks], aB, 0, 0, 0);
      aC = __builtin_amdgcn_mfma_f32_16x16x32_bf16(Hh, BUl[ks], aC, 0, 0, 0);
    }

    // ---- gather + cell (v16 verbatim numerics)
    f32x4 g4 = (aA + aB) + aC;
    xpose4(g4, b2, b3);
    float gi = g4[0] + __uint_as_float(gxu[0] & 0xFFFF0000u) + bi;
    float gf = g4[1] + __uint_as_float(gxu[0] << 16)          + bfo;
    float gg = g4[2] + __uint_as_float(gxu[1] & 0xFFFF0000u) + bg;
    float go = g4[3] + __uint_as_float(gxu[1] << 16)          + bo;
    float it = sigm(gi), ft = sigm(gf), ot = sigm(go);
    float gt = tanh_f(gg);
    float cnew = ft * creg + it * gt;
    float hnew = ot * tanh_f(cnew);
    const bool act = (t < len);
    if (act) { creg = cnew; hreg = hnew; }
    {
      u32x2 pv = {packbf(hreg * PKEEP), (u32)(t + 1)};
      dev_st_u32x2(hbuf + (par ^ 1) * PLANE_U32 + m * REGION_U32 + row_l * 512 + ghc_w * 2, pv);
    }

    // ---- out store + flag prefetch for t+1 (v16 verbatim), bottom drain kept
    out[(long)t * (BATCH * HID) + gb * HID + ghc_w] = act ? hnew : 0.0f;
    if (t + 1 < T_STEPS) f = coh_ld_i32(flagp);

    asm volatile("s_waitcnt vmcnt(0)" ::: "memory");
    __builtin_amdgcn_sched_barrier(0);
  }

  out[(long)T_STEPS * (BATCH * HID) + gb * HID + ghc_w] = hreg;
  out[(long)T_STEPS * (BATCH * HID) + BATCH * HID + gb * HID + ghc_w] = creg;
}

__global__ __launch_bounds__(256, 1) void lstm_fused_v18(
    const float* __restrict__ x, const int* __restrict__ lens,
    const float* __restrict__ W, const float* __restrict__ U,
    const float* __restrict__ bih, const float* __restrict__ bhh,
    float* __restrict__ out, u32* __restrict__ hbuf,
    u32* __restrict__ Gxb, int* __restrict__ xf) {
  __shared__ u32 smem[2 * RPG * HID];  // 32KB, role-dependent
  if (blockIdx.x < NH) h_role(lens, U, bih, bhh, out, hbuf, Gxb, xf, smem);
  else                 x_role(x, W, Gxb, xf, smem);
}

// ================= v8 fallback (proven), verbatim ============================
template <int MODE>
__device__ __forceinline__ void recur_body8(
    const float* __restrict__ x, const int* __restrict__ lens,
    const float* __restrict__ W, const float* __restrict__ U,
    const float* __restrict__ bih, const float* __restrict__ bhh,
    float* __restrict__ out, u32* __restrict__ hbuf, const u32* __restrict__ xpk) {
  const int wg = blockIdx.x, tid = threadIdx.x;
  const int m = wg >> 4, n = wg & 15;
  const int lane = tid & 63, wave = tid >> 6;
  const int n16 = lane & 15, kgrp = lane >> 4;

  const int ghc_w = n * 16 + wave * 4 + (n16 & 3);
  const int grow = (n16 >> 2) * HID + ghc_w;
  s16x8 BUh[8], BUl[8], BWh[8], BWl[8];
#pragma unroll
  for (int ks = 0; ks < 8; ++ks) {
    const int base = grow * DIM + ks * 32 + kgrp * 8;
#pragma unroll
    for (int e = 0; e < 8; ++e) {
      float uv = U[base + e];
      u16 uh = f2bf_rne(uv);
      BUh[ks][e] = (short)uh;
      BUl[ks][e] = (short)f2bf_rne(uv - bf2f(uh));
      float wv = W[base + e];
      u16 wh = f2bf_rne(wv);
      BWh[ks][e] = (short)wh;
      BWl[ks][e] = (short)f2bf_rne(wv - bf2f(wh));
    }
  }

  const bool b2 = (lane >> 2) & 1, b3 = (lane >> 3) & 1;
  const int row_l = kgrp * 4 + (n16 >> 2);
  const int gb = m * RPG + row_l;
  const float bi  = bih[0 * HID + ghc_w] + bhh[0 * HID + ghc_w];
  const float bfo = bih[1 * HID + ghc_w] + bhh[1 * HID + ghc_w];
  const float bg  = bih[2 * HID + ghc_w] + bhh[2 * HID + ghc_w];
  const float bo  = bih[3 * HID + ghc_w] + bhh[3 * HID + ghc_w];
  const int len = lens[gb];
  float hreg = 0.0f, creg = 0.0f;

  const int rh = tid >> 7, p = tid & 127;

  __shared__ u32 hstage[2][RPG * HID];
  __shared__ u32 xstage[2][RPG * HID];

  {
    const int R = wave * 4;
    const long tb = (long)(m * RPG) * DIM;
#pragma unroll
    for (int r = 0; r < 4; ++r) {
      const long src = tb + (long)(R + r) * DIM + 4 * (lane ^ ((R + r) & 15));
      if constexpr (MODE == 0) gload_lds16(xpk + src, &xstage[0][(R + r) * HID]);
      else                     gload_lds16((const u32*)x + src, &xstage[0][(R + r) * HID]);
    }
  }

  for (int t = 0; t < T_STEPS; ++t) {
    const int par = t & 1;
    u32x4 P[8];
    {
      const u32* rb = hbuf + par * PLANE_U32 + m * REGION_U32 + rh * (8 * 512) + p * 4;
      for (;;) {
#pragma unroll
        for (int j = 0; j < 8; ++j)
          asm volatile("global_load_dwordx4 %0, %1, off sc0 sc1"
                       : "=v"(P[j]) : "v"(rb + j * 512) : "memory");
        asm volatile("s_waitcnt vmcnt(0)" ::: "memory");
        if (t == 0) break;
        bool stale = false;
#pragma unroll
        for (int j = 0; j < 8; ++j)
          stale |= (P[j][1] != (u32)t) || (P[j][3] != (u32)t);
        if (!__any(stale)) break;
      }
    }
    __builtin_amdgcn_sched_barrier(0);

#pragma unroll
    for (int j = 0; j < 8; ++j) {
      const int row = rh * 8 + j;
      const int byte = (row * 1024 + p * 8) ^ (row << 4);
      u32x2 v = {P[j][0], P[j][2]};
      *(u32x2*)((char*)hstage[par] + byte) = v;
    }
    __syncthreads();

    const int swz = n16 << 4;
    f32x4 ah = {0.f, 0.f, 0.f, 0.f}, ax = {0.f, 0.f, 0.f, 0.f};
#pragma unroll
    for (int ks = 0; ks < 8; ++ks) {
      const int bb = n16 * 1024 + (kgrp * 8 + ks * 32) * 4;
      u32x4 h0 = *(const u32x4*)((const char*)hstage[par] + (bb ^ swz));
      u32x4 h1 = *(const u32x4*)((const char*)hstage[par] + ((bb + 16) ^ swz));
      s16x8 Hh, Hl, Xh, Xl;
      unpack8(h0, h1, Hh, Hl);
      if constexpr (MODE == 0) {
        u32x4 x0 = *(const u32x4*)((const char*)xstage[par] + (bb ^ swz));
        u32x4 x1 = *(const u32x4*)((const char*)xstage[par] + ((bb + 16) ^ swz));
        unpack8(x0, x1, Xh, Xl);
      } else {
        f32x4 f0 = *(const f32x4*)((const char*)xstage[par] + (bb ^ swz));
        f32x4 f1 = *(const f32x4*)((const char*)xstage[par] + ((bb + 16) ^ swz));
#pragma unroll
        for (int e = 0; e < 8; ++e) {
          float v = (e < 4 ? f0[e] : f1[e - 4]) * PKEEP;
          unsigned hb = __float_as_uint(v) & 0xFFFF0000u;
          Xh[e] = (short)(hb >> 16);
          Xl[e] = (short)(u16)(__float_as_uint(v - __uint_as_float(hb)) >> 16);
        }
      }
      ah = __builtin_amdgcn_mfma_f32_16x16x32_bf16(Hh, BUh[ks], ah, 0, 0, 0);
      ax = __builtin_amdgcn_mfma_f32_16x16x32_bf16(Xh, BWh[ks], ax, 0, 0, 0);
      ah = __builtin_amdgcn_mfma_f32_16x16x32_bf16(Hl, BUh[ks], ah, 0, 0, 0);
      ax = __builtin_amdgcn_mfma_f32_16x16x32_bf16(Xl, BWh[ks], ax, 0, 0, 0);
      ah = __builtin_amdgcn_mfma_f32_16x16x32_bf16(Hh, BUl[ks], ah, 0, 0, 0);
      ax = __builtin_amdgcn_mfma_f32_16x16x32_bf16(Xh, BWl[ks], ax, 0, 0, 0);
    }

    f32x4 g4 = ah + ax;
    xpose4(g4, b2, b3);

    float gi = g4[0] + bi, gf = g4[1] + bfo, gg = g4[2] + bg, go = g4[3] + bo;
    float it = sigm(gi), ft = sigm(gf), ot = sigm(go);
    float gt = tanh_f(gg);
    float cnew = ft * creg + it * gt;
    float hnew = ot * tanh_f(cnew);
    const bool act = (t < len);
    if (act) { creg = cnew; hreg = hnew; }
    {
      u32x2 pv = {packbf(hreg * PKEEP), (u32)(t + 1)};
      dev_st_u32x2(hbuf + (par ^ 1) * PLANE_U32 + m * REGION_U32 + row_l * 512 + ghc_w * 2, pv);
    }

    if (t + 1 < T_STEPS) {
      const int R = wave * 4;
      const long tb = (long)(t + 1) * (BATCH * DIM) + (long)(m * RPG) * DIM;
#pragma unroll
      for (int r = 0; r < 4; ++r) {
        const long src = tb + (long)(R + r) * DIM + 4 * (lane ^ ((R + r) & 15));
        if constexpr (MODE == 0) gload_lds16(xpk + src, &xstage[par ^ 1][(R + r) * HID]);
        else                     gload_lds16((const u32*)x + src, &xstage[par ^ 1][(R + r) * HID]);
      }
    }
    out[(long)t * (BATCH * HID) + gb * HID + ghc_w] = act ? hnew : 0.0f;

    asm volatile("s_waitcnt vmcnt(0)" ::: "memory");
    __builtin_amdgcn_sched_barrier(0);
  }

  out[(long)T_STEPS * (BATCH * HID) + gb * HID + ghc_w] = hreg;
  out[(long)T_STEPS * (BATCH * HID) + BATCH * HID + gb * HID + ghc_w] = creg;
}

#define RECUR_PARAMS                                                          \
  const float* __restrict__ x, const int* __restrict__ lens,                  \
  const float* __restrict__ W, const float* __restrict__ U,                   \
  const float* __restrict__ bih, const float* __restrict__ bhh,               \
  float* __restrict__ out, u32* __restrict__ hbuf, const u32* __restrict__ xpk
#define RECUR_ARGS x, lens, W, U, bih, bhh, out, hbuf, xpk

__global__ __launch_bounds__(256, 1) void lstm_recur_v8_xpk(RECUR_PARAMS) { recur_body8<0>(RECUR_ARGS); }
__global__ __launch_bounds__(256, 1) void lstm_recur_v8_dir(RECUR_PARAMS) { recur_body8<1>(RECUR_ARGS); }

extern "C" void kernel_launch(void* const* d_in, const int* in_sizes, int n_in,
                              void* d_out, int out_size, void* d_ws, size_t ws_size,
                              hipStream_t stream) {
  const float* x   = (const float*)d_in[0];
  const int*   len = (const int*)d_in[1];
  const float* W   = (const float*)d_in[2];
  const float* U   = (const float*)d_in[3];
  const float* bih = (const float*)d_in[4];
  const float* bhh = (const float*)d_in[5];
  float* out = (float*)d_out;
  char*  ws  = (char*)d_ws;
  int* xf   = (int*)(ws + XF_OFF);
  u32* hbuf = (u32*)(ws + HBUF_OFF);
  char* big = ws + BIG_OFF;

  lstm_zero_ws<<<dim3((ZERO_U32 + 255) / 256), dim3(256), 0, stream>>>((u32*)ws);

  const size_t need_gx = (size_t)BIG_OFF + (size_t)T_STEPS * BATCH * 512 * 4;  // ~257MB
  const size_t need_xp = (size_t)BIG_OFF + (size_t)XEL * 4;                    // ~129MB
  if (ws_size >= need_gx) {
    u32* Gxb = (u32*)big;
    lstm_fused_v18<<<dim3(NH + NX), dim3(256), 0, stream>>>(x, len, W, U, bih, bhh,
                                                            out, hbuf, Gxb, xf);
  } else if (ws_size >= need_xp) {
    u32* xpk = (u32*)big;
    lstm_xpack<<<dim3(32768), dim3(256), 0, stream>>>(x, xpk);
    lstm_recur_v8_xpk<<<dim3(64), dim3(256), 0, stream>>>(x, len, W, U, bih, bhh, out, hbuf, xpk);
  } else {
    lstm_recur_v8_dir<<<dim3(64), dim3(256), 0, stream>>>(x, len, W, U, bih, bhh, out, hbuf, nullptr);
  }
}